// Round 2
// baseline (308.964 us; speedup 1.0000x reference)
//
#include <hip/hip_runtime.h>

#define BATCH 512
#define V 6890
#define NJ 24
#define VH (V/2)   // 3445 float2 per feature row

#define SD_N (V*30)
#define VT_N (V*3)
#define W_N  (V*24)
#define TOT_PK (SD_N+VT_N+W_N)   // 392730 floats

// workspace layout (float indices)
#define A_OFF   0          // BATCH*288 fp32 skinning matrices
#define BS_OFF  147456     // BATCH*16 per-batch scalars {b0, b0*beta[1..10], transl[0..2], pad}
#define JT_OFF  155648     // 72  = Jr @ v_template
#define JS_OFF  155720     // 720 = Jr @ shapedirs
#define PK_OFF  156672     // transposed fp32 region, rows stride V:
                           //   sd row j at j*V; vt row k at (30+k)*V; W row n at (33+n)*V

__device__ const int d_par[NJ] = {-1,0,0,0,1,2,3,4,5,6,7,8,9,9,9,12,13,14,16,17,18,19,20,21};

// ---------------- prep: transpose per-vertex data to [feature][V] fp32 ----------------
__global__ __launch_bounds__(256) void prep_k(
    const float* __restrict__ sd, const float* __restrict__ vt, const float* __restrict__ W,
    float* __restrict__ dst)
{
  int i = blockIdx.x*256 + threadIdx.x;
  if (i >= TOT_PK) return;
  float val;
  if (i < SD_N){ int j=i/V, v=i-j*V; val = sd[v*30+j]; }
  else if (i < SD_N+VT_N){ int o=i-SD_N; int j=o/V, v=o-j*V; val = vt[v*3+j]; }
  else { int o=i-SD_N-VT_N; int j=o/V, v=o-j*V; val = W[v*24+j]; }
  dst[i] = val;
}

// ---------------- joint-regressor contraction: JT[24*3], JS[24*3*10] ----------------
__global__ __launch_bounds__(256) void jreg_k(
    const float* __restrict__ Jr, const float* __restrict__ sd, const float* __restrict__ vt,
    float* __restrict__ JTo, float* __restrict__ JSo)
{
  const int j = blockIdx.x;   // 24
  const int c = blockIdx.y;   // 33: 0..2 -> v_template col, 3..32 -> shapedirs col
  const int t = threadIdx.x;
  float acc = 0.f;
  for (int v=t; v<V; v+=256){
    float jr = Jr[j*V+v];
    float x = (c<3) ? vt[v*3+c] : sd[v*30+(c-3)];
    acc = fmaf(jr, x, acc);
  }
  __shared__ float red[256];
  red[t]=acc; __syncthreads();
  for (int s=128;s>0;s>>=1){ if(t<s) red[t]+=red[t+s]; __syncthreads(); }
  if (t==0){
    if (c<3) JTo[j*3+c]=red[0];
    else {
      int idx=c-3, k=idx/10, l=idx-10*(idx/10);
      JSo[(j*3+k)*10+l] = red[0];
    }
  }
}

// ---------------- per-batch: joints, rodrigues, chain, A, J_transformed ----------------
__global__ __launch_bounds__(64) void batch_k(
    const float* __restrict__ betas, const float* __restrict__ body_pose,
    const float* __restrict__ go, const float* __restrict__ transl,
    const float* __restrict__ JT, const float* __restrict__ JS,
    float* __restrict__ A, float* __restrict__ bsc, float* __restrict__ jout)
{
  const int b = blockIdx.x;
  const int t = threadIdx.x;
  __shared__ float lb[11];
  __shared__ float lJ[72];
  __shared__ float lR[NJ*9];
  __shared__ float lL[NJ*12];
  __shared__ float lW[NJ*12];
  if (t < 11) lb[t] = betas[b*11+t];
  __syncthreads();
  const float b0 = lb[0];
  // joints J[b,j,k] = b0*(JT + sum_l beta_l * JS)
  for (int idx=t; idx<72; idx+=64){
    float s = JT[idx];
    #pragma unroll
    for (int l=0;l<10;l++) s = fmaf(lb[1+l], JS[idx*10+l], s);
    lJ[idx] = b0*s;
  }
  // per-batch scalars for main kernel
  if (t==0) bsc[b*16] = b0;
  if (t>=1 && t<11) bsc[b*16+t] = b0*lb[t];
  if (t<3) bsc[b*16+11+t] = transl[b*3+t];
  // rodrigues (matches reference: angle = ||p + 1e-8||, dir = p/angle)
  if (t < NJ){
    float p0,p1,p2;
    if (t==0){ p0=go[b*3+0]; p1=go[b*3+1]; p2=go[b*3+2]; }
    else { int o=b*69+(t-1)*3; p0=body_pose[o]; p1=body_pose[o+1]; p2=body_pose[o+2]; }
    float a0=p0+1e-8f, a1=p1+1e-8f, a2=p2+1e-8f;
    float angle = sqrtf(a0*a0+a1*a1+a2*a2);
    float inv = 1.0f/angle;
    float rx=p0*inv, ry=p1*inv, rz=p2*inv;
    float sn = sinf(angle), cs = cosf(angle), mc = 1.0f-cs;
    float K[9] = {0.f,-rz,ry, rz,0.f,-rx, -ry,rx,0.f};
    float KK[9];
    #pragma unroll
    for (int r=0;r<3;r++)
      #pragma unroll
      for (int c=0;c<3;c++)
        KK[r*3+c] = K[r*3+0]*K[0+c] + K[r*3+1]*K[3+c] + K[r*3+2]*K[6+c];
    #pragma unroll
    for (int e=0;e<9;e++){
      float ident = (e==0||e==4||e==8)?1.0f:0.0f;
      lR[t*9+e] = ident + sn*K[e] + mc*KK[e];
    }
  }
  __syncthreads();
  // local transforms [R | rel]
  for (int idx=t; idx<288; idx+=64){
    int j = idx/12, rc = idx-12*j, r = rc>>2, c = rc&3;
    float val;
    if (c<3) val = lR[j*9 + r*3 + c];
    else {
      int p = (j==0) ? 0 : d_par[j];
      val = (j==0) ? lJ[r] : (lJ[j*3+r] - lJ[p*3+r]);
    }
    lL[idx] = val;
  }
  __syncthreads();
  if (t<12) lW[t] = lL[t];
  __syncthreads();
  // kinematic chain, 12 lanes compose one 3x4 per step
  for (int i=1;i<NJ;i++){
    if (t<12){
      int p = d_par[i];
      int r = t>>2, c = t&3;
      float s = lW[p*12+r*4+0]*lL[i*12+0+c]
              + lW[p*12+r*4+1]*lL[i*12+4+c]
              + lW[p*12+r*4+2]*lL[i*12+8+c];
      if (c==3) s += lW[p*12+r*4+3];
      lW[i*12+t] = s;
    }
    __syncthreads();
  }
  // J_transformed (output 1) -- full 72 elements
  for (int idx=t; idx<72; idx+=64){
    int j=idx/3, k=idx-3*j;
    jout[b*72+idx] = lW[j*12+k*4+3];
  }
  // A = world with t-col -= R_world @ J
  for (int idx=t; idx<288; idx+=64){
    int n=idx/12, rc=idx-12*n, r=rc>>2, c=rc&3;
    float val = lW[n*12+rc];
    if (c==3){
      val -= lW[n*12+r*4+0]*lJ[n*3+0] + lW[n*12+r*4+1]*lJ[n*3+1] + lW[n*12+r*4+2]*lJ[n*3+2];
    }
    A[b*288+idx] = val;
  }
}

// ---------------- main LBS: 2 adjacent vertices x 8 batches per thread ----------------
__global__ __launch_bounds__(256) void main_k(
    const float* __restrict__ A, const float* __restrict__ bsc,
    const float2* __restrict__ pk, float* __restrict__ out)
{
  const int tid = threadIdx.x;
  const int v0 = blockIdx.x*512 + 2*tid;
  if (v0 >= V) return;
  const int vh = v0 >> 1;

  float2 sd[30];
#pragma unroll
  for (int j=0;j<30;j++) sd[j] = pk[j*VH + vh];
  float2 vt3[3];
#pragma unroll
  for (int k=0;k<3;k++) vt3[k] = pk[(30+k)*VH + vh];
  float2 w[NJ];
#pragma unroll
  for (int n=0;n<NJ;n++) w[n] = pk[(33+n)*VH + vh];

  for (int bi=0; bi<8; bi++){
    const int b = blockIdx.y*8 + bi;
    const float* __restrict__ bs = bsc + b*16;
    const float sb0 = bs[0];
    float2 vs[3];
#pragma unroll
    for (int k=0;k<3;k++){
      float ax = sb0*vt3[k].x, ay = sb0*vt3[k].y;
#pragma unroll
      for (int l=0;l<10;l++){
        const float c = bs[1+l];
        ax = fmaf(c, sd[k*10+l].x, ax);
        ay = fmaf(c, sd[k*10+l].y, ay);
      }
      vs[k] = make_float2(ax, ay);
    }
    const float* __restrict__ Ab = A + b*288;
    float y0x=0.f,y0y=0.f,y1x=0.f,y1y=0.f,y2x=0.f,y2y=0.f;
#pragma unroll
    for (int n=0;n<NJ;n++){
      const float* __restrict__ an = Ab + n*12;
      const float wx = w[n].x, wy = w[n].y;
      float tt;
      tt = fmaf(an[2], vs[2].x, fmaf(an[1], vs[1].x, fmaf(an[0], vs[0].x, an[3])));
      y0x = fmaf(wx, tt, y0x);
      tt = fmaf(an[2], vs[2].y, fmaf(an[1], vs[1].y, fmaf(an[0], vs[0].y, an[3])));
      y0y = fmaf(wy, tt, y0y);
      tt = fmaf(an[6], vs[2].x, fmaf(an[5], vs[1].x, fmaf(an[4], vs[0].x, an[7])));
      y1x = fmaf(wx, tt, y1x);
      tt = fmaf(an[6], vs[2].y, fmaf(an[5], vs[1].y, fmaf(an[4], vs[0].y, an[7])));
      y1y = fmaf(wy, tt, y1y);
      tt = fmaf(an[10], vs[2].x, fmaf(an[9], vs[1].x, fmaf(an[8], vs[0].x, an[11])));
      y2x = fmaf(wx, tt, y2x);
      tt = fmaf(an[10], vs[2].y, fmaf(an[9], vs[1].y, fmaf(an[8], vs[0].y, an[11])));
      y2y = fmaf(wy, tt, y2y);
    }
    const float t0 = bs[11], t1 = bs[12], t2 = bs[13];
    y0x+=t0; y0y+=t0; y1x+=t1; y1y+=t1; y2x+=t2; y2y+=t2;
    // layout: [v0.x v0.y v0.z v1.x v1.y v1.z] at (b*V+v0)*3, even index -> float2 aligned
    float2* o2 = (float2*)(out + (b*V + v0)*3);
    o2[0] = make_float2(y0x, y1x);
    o2[1] = make_float2(y2x, y0y);
    o2[2] = make_float2(y1y, y2y);
  }
}

extern "C" void kernel_launch(void* const* d_in, const int* in_sizes, int n_in,
                              void* d_out, int out_size, void* d_ws, size_t ws_size,
                              hipStream_t stream)
{
  const float* betas     = (const float*)d_in[0];
  const float* body_pose = (const float*)d_in[1];
  const float* go        = (const float*)d_in[2];
  const float* transl    = (const float*)d_in[3];
  const float* sdirs     = (const float*)d_in[4];
  const float* vtempl    = (const float*)d_in[5];
  const float* Jr        = (const float*)d_in[6];
  const float* lw        = (const float*)d_in[7];
  float* wsf = (float*)d_ws;
  float* out = (float*)d_out;

  hipLaunchKernelGGL(prep_k, dim3((TOT_PK+255)/256), dim3(256), 0, stream,
                     sdirs, vtempl, lw, wsf+PK_OFF);
  hipLaunchKernelGGL(jreg_k, dim3(24,33), dim3(256), 0, stream,
                     Jr, sdirs, vtempl, wsf+JT_OFF, wsf+JS_OFF);
  hipLaunchKernelGGL(batch_k, dim3(BATCH), dim3(64), 0, stream,
                     betas, body_pose, go, transl, wsf+JT_OFF, wsf+JS_OFF,
                     wsf+A_OFF, wsf+BS_OFF, out + BATCH*V*3);
  hipLaunchKernelGGL(main_k, dim3((V+511)/512, BATCH/8), dim3(256), 0, stream,
                     wsf+A_OFF, wsf+BS_OFF, (const float2*)(wsf+PK_OFF), out);
}

// Round 3
// 149.510 us; speedup vs baseline: 2.0665x; 2.0665x over previous
//
#include <hip/hip_runtime.h>

#define BATCH 512
#define V 6890
#define NJ 24
#define VH (V/2)   // 3445 float2 per feature row

#define SD_N (V*30)
#define VT_N (V*3)
#define W_N  (V*24)
#define TOT_PK (SD_N+VT_N+W_N)   // 392730 floats

// workspace layout (float indices)
// A layout: 128 groups of 4 batches: off = (b>>2)*1152 + n*48 + (b&3)*12 + j
#define A_OFF   0          // BATCH*288 fp32 skinning matrices (grouped)
#define BS_OFF  147456     // BATCH*16 per-batch scalars {b0, b0*beta[1..10], transl[0..2], pad}
#define JT_OFF  155648     // 72  = Jr @ v_template
#define JS_OFF  155720     // 720 = Jr @ shapedirs
#define PK_OFF  156672     // transposed fp32, rows stride V:
                           //   sd row j at j*V; vt row k at (30+k)*V; W row n at (33+n)*V

__device__ const int d_par[NJ] = {-1,0,0,0,1,2,3,4,5,6,7,8,9,9,9,12,13,14,16,17,18,19,20,21};

// ---------------- prep: transpose per-vertex data to [feature][V] fp32 ----------------
__global__ __launch_bounds__(256) void prep_k(
    const float* __restrict__ sd, const float* __restrict__ vt, const float* __restrict__ W,
    float* __restrict__ dst)
{
  int i = blockIdx.x*256 + threadIdx.x;
  if (i >= TOT_PK) return;
  float val;
  if (i < SD_N){ int j=i/V, v=i-j*V; val = sd[v*30+j]; }
  else if (i < SD_N+VT_N){ int o=i-SD_N; int j=o/V, v=o-j*V; val = vt[v*3+j]; }
  else { int o=i-SD_N-VT_N; int j=o/V, v=o-j*V; val = W[v*24+j]; }
  dst[i] = val;
}

// ---------------- joint-regressor contraction (reads transposed pk, coalesced) --------
__global__ __launch_bounds__(256) void jreg_k(
    const float* __restrict__ Jr, const float* __restrict__ pk,
    float* __restrict__ JTo, float* __restrict__ JSo)
{
  const int j = blockIdx.x;   // 24
  const int c = blockIdx.y;   // 33: 0..2 -> v_template col, 3..32 -> shapedirs col
  const int t = threadIdx.x;
  const float* __restrict__ col = (c<3) ? (pk + (30+c)*V) : (pk + (c-3)*V);
  float acc = 0.f;
  for (int v=t; v<V; v+=256){
    acc = fmaf(Jr[j*V+v], col[v], acc);
  }
  __shared__ float red[256];
  red[t]=acc; __syncthreads();
  for (int s=128;s>0;s>>=1){ if(t<s) red[t]+=red[t+s]; __syncthreads(); }
  if (t==0){
    if (c<3) JTo[j*3+c]=red[0];
    else {
      int idx=c-3, k=idx/10, l=idx-10*(idx/10);
      JSo[(j*3+k)*10+l] = red[0];
    }
  }
}

// ---------------- per-batch: joints, rodrigues, chain, A (grouped), J_transformed -----
__global__ __launch_bounds__(64) void batch_k(
    const float* __restrict__ betas, const float* __restrict__ body_pose,
    const float* __restrict__ go, const float* __restrict__ transl,
    const float* __restrict__ JT, const float* __restrict__ JS,
    float* __restrict__ A, float* __restrict__ bsc, float* __restrict__ jout)
{
  const int b = blockIdx.x;
  const int t = threadIdx.x;
  __shared__ float lb[11];
  __shared__ float lJ[72];
  __shared__ float lR[NJ*9];
  __shared__ float lL[NJ*12];
  __shared__ float lW[NJ*12];
  if (t < 11) lb[t] = betas[b*11+t];
  __syncthreads();
  const float b0 = lb[0];
  for (int idx=t; idx<72; idx+=64){
    float s = JT[idx];
    #pragma unroll
    for (int l=0;l<10;l++) s = fmaf(lb[1+l], JS[idx*10+l], s);
    lJ[idx] = b0*s;
  }
  if (t==0) bsc[b*16] = b0;
  if (t>=1 && t<11) bsc[b*16+t] = b0*lb[t];
  if (t<3) bsc[b*16+11+t] = transl[b*3+t];
  if (t < NJ){
    float p0,p1,p2;
    if (t==0){ p0=go[b*3+0]; p1=go[b*3+1]; p2=go[b*3+2]; }
    else { int o=b*69+(t-1)*3; p0=body_pose[o]; p1=body_pose[o+1]; p2=body_pose[o+2]; }
    float a0=p0+1e-8f, a1=p1+1e-8f, a2=p2+1e-8f;
    float angle = sqrtf(a0*a0+a1*a1+a2*a2);
    float inv = 1.0f/angle;
    float rx=p0*inv, ry=p1*inv, rz=p2*inv;
    float sn = sinf(angle), cs = cosf(angle), mc = 1.0f-cs;
    float K[9] = {0.f,-rz,ry, rz,0.f,-rx, -ry,rx,0.f};
    float KK[9];
    #pragma unroll
    for (int r=0;r<3;r++)
      #pragma unroll
      for (int c=0;c<3;c++)
        KK[r*3+c] = K[r*3+0]*K[0+c] + K[r*3+1]*K[3+c] + K[r*3+2]*K[6+c];
    #pragma unroll
    for (int e=0;e<9;e++){
      float ident = (e==0||e==4||e==8)?1.0f:0.0f;
      lR[t*9+e] = ident + sn*K[e] + mc*KK[e];
    }
  }
  __syncthreads();
  for (int idx=t; idx<288; idx+=64){
    int j = idx/12, rc = idx-12*j, r = rc>>2, c = rc&3;
    float val;
    if (c<3) val = lR[j*9 + r*3 + c];
    else {
      int p = (j==0) ? 0 : d_par[j];
      val = (j==0) ? lJ[r] : (lJ[j*3+r] - lJ[p*3+r]);
    }
    lL[idx] = val;
  }
  __syncthreads();
  if (t<12) lW[t] = lL[t];
  __syncthreads();
  for (int i=1;i<NJ;i++){
    if (t<12){
      int p = d_par[i];
      int r = t>>2, c = t&3;
      float s = lW[p*12+r*4+0]*lL[i*12+0+c]
              + lW[p*12+r*4+1]*lL[i*12+4+c]
              + lW[p*12+r*4+2]*lL[i*12+8+c];
      if (c==3) s += lW[p*12+r*4+3];
      lW[i*12+t] = s;
    }
    __syncthreads();
  }
  for (int idx=t; idx<72; idx+=64){
    int j=idx/3, k=idx-3*j;
    jout[b*72+idx] = lW[j*12+k*4+3];
  }
  // A (grouped layout) = world with t-col -= R_world @ J
  const int g = b>>2, q = b&3;
  float* __restrict__ Ab = A + g*1152 + q*12;
  for (int idx=t; idx<288; idx+=64){
    int n=idx/12, rc=idx-12*n, r=rc>>2, c=rc&3;
    float val = lW[n*12+rc];
    if (c==3){
      val -= lW[n*12+r*4+0]*lJ[n*3+0] + lW[n*12+r*4+1]*lJ[n*3+1] + lW[n*12+r*4+2]*lJ[n*3+2];
    }
    Ab[n*48 + rc] = val;
  }
}

// ---------------- main LBS: 1 vertex-pair x 4 block-shared batches per thread ---------
__global__ __launch_bounds__(256) void main_k(
    const float* __restrict__ A, const float* __restrict__ bsc,
    const float2* __restrict__ pk, float* __restrict__ out)
{
  const int vh = blockIdx.x*256 + threadIdx.x;
  if (vh >= VH) return;
  const int bg = blockIdx.y;                 // batch group of 4 (shared by block)
  const float* __restrict__ Ag = A + bg*1152;
  const float* __restrict__ bs = bsc + bg*64;

  const float2 vt0 = pk[30*VH + vh];
  const float2 vt1 = pk[31*VH + vh];
  const float2 vt2 = pk[32*VH + vh];

  float2 vs[4][3];
#pragma unroll
  for (int q=0;q<4;q++){
    const float b0 = bs[q*16];
    vs[q][0] = make_float2(b0*vt0.x, b0*vt0.y);
    vs[q][1] = make_float2(b0*vt1.x, b0*vt1.y);
    vs[q][2] = make_float2(b0*vt2.x, b0*vt2.y);
  }
#pragma unroll
  for (int l=0;l<10;l++){
    const float2 s0 = pk[(0*10+l)*VH + vh];
    const float2 s1 = pk[(1*10+l)*VH + vh];
    const float2 s2 = pk[(2*10+l)*VH + vh];
#pragma unroll
    for (int q=0;q<4;q++){
      const float c = bs[q*16+1+l];
      vs[q][0].x = fmaf(c, s0.x, vs[q][0].x); vs[q][0].y = fmaf(c, s0.y, vs[q][0].y);
      vs[q][1].x = fmaf(c, s1.x, vs[q][1].x); vs[q][1].y = fmaf(c, s1.y, vs[q][1].y);
      vs[q][2].x = fmaf(c, s2.x, vs[q][2].x); vs[q][2].y = fmaf(c, s2.y, vs[q][2].y);
    }
  }

  float y[4][6];
#pragma unroll
  for (int q=0;q<4;q++)
#pragma unroll
    for (int i=0;i<6;i++) y[q][i] = 0.f;

#pragma unroll 4
  for (int n=0;n<NJ;n++){
    const float2 w = pk[(33+n)*VH + vh];
#pragma unroll
    for (int q=0;q<4;q++){
      const float* __restrict__ an = Ag + n*48 + q*12;   // block-uniform -> s_load
      float tt;
      tt = fmaf(an[2], vs[q][2].x, fmaf(an[1], vs[q][1].x, fmaf(an[0], vs[q][0].x, an[3])));
      y[q][0] = fmaf(w.x, tt, y[q][0]);
      tt = fmaf(an[2], vs[q][2].y, fmaf(an[1], vs[q][1].y, fmaf(an[0], vs[q][0].y, an[3])));
      y[q][1] = fmaf(w.y, tt, y[q][1]);
      tt = fmaf(an[6], vs[q][2].x, fmaf(an[5], vs[q][1].x, fmaf(an[4], vs[q][0].x, an[7])));
      y[q][2] = fmaf(w.x, tt, y[q][2]);
      tt = fmaf(an[6], vs[q][2].y, fmaf(an[5], vs[q][1].y, fmaf(an[4], vs[q][0].y, an[7])));
      y[q][3] = fmaf(w.y, tt, y[q][3]);
      tt = fmaf(an[10], vs[q][2].x, fmaf(an[9], vs[q][1].x, fmaf(an[8], vs[q][0].x, an[11])));
      y[q][4] = fmaf(w.x, tt, y[q][4]);
      tt = fmaf(an[10], vs[q][2].y, fmaf(an[9], vs[q][1].y, fmaf(an[8], vs[q][0].y, an[11])));
      y[q][5] = fmaf(w.y, tt, y[q][5]);
    }
  }

  const int v0 = 2*vh;
#pragma unroll
  for (int q=0;q<4;q++){
    const float t0 = bs[q*16+11], t1 = bs[q*16+12], t2 = bs[q*16+13];
    const int b = bg*4 + q;
    float2* __restrict__ o2 = (float2*)(out + (b*V + v0)*3);
    o2[0] = make_float2(y[q][0]+t0, y[q][2]+t1);
    o2[1] = make_float2(y[q][4]+t2, y[q][1]+t0);
    o2[2] = make_float2(y[q][3]+t1, y[q][5]+t2);
  }
}

extern "C" void kernel_launch(void* const* d_in, const int* in_sizes, int n_in,
                              void* d_out, int out_size, void* d_ws, size_t ws_size,
                              hipStream_t stream)
{
  const float* betas     = (const float*)d_in[0];
  const float* body_pose = (const float*)d_in[1];
  const float* go        = (const float*)d_in[2];
  const float* transl    = (const float*)d_in[3];
  const float* sdirs     = (const float*)d_in[4];
  const float* vtempl    = (const float*)d_in[5];
  const float* Jr        = (const float*)d_in[6];
  const float* lw        = (const float*)d_in[7];
  float* wsf = (float*)d_ws;
  float* out = (float*)d_out;

  hipLaunchKernelGGL(prep_k, dim3((TOT_PK+255)/256), dim3(256), 0, stream,
                     sdirs, vtempl, lw, wsf+PK_OFF);
  hipLaunchKernelGGL(jreg_k, dim3(24,33), dim3(256), 0, stream,
                     Jr, wsf+PK_OFF, wsf+JT_OFF, wsf+JS_OFF);
  hipLaunchKernelGGL(batch_k, dim3(BATCH), dim3(64), 0, stream,
                     betas, body_pose, go, transl, wsf+JT_OFF, wsf+JS_OFF,
                     wsf+A_OFF, wsf+BS_OFF, out + BATCH*V*3);
  hipLaunchKernelGGL(main_k, dim3((VH+255)/256, BATCH/4), dim3(256), 0, stream,
                     wsf+A_OFF, wsf+BS_OFF, (const float2*)(wsf+PK_OFF), out);
}